// Round 1
// baseline (574.821 us; speedup 1.0000x reference)
//
#include <hip/hip_runtime.h>

// ---------------- CSR build ----------------

__global__ __launch_bounds__(256) void k_count(const int* __restrict__ dst, int* __restrict__ cnt, int E){
    int e = blockIdx.x*256 + threadIdx.x;
    if (e < E) atomicAdd(&cnt[dst[e]], 1);
}

__global__ __launch_bounds__(256) void k_scan1(const int* __restrict__ cnt, int* __restrict__ rs,
                                               int* __restrict__ part, int N){
    __shared__ int sm[256];
    int t = threadIdx.x;
    int i = blockIdx.x*256 + t;
    int c = (i < N) ? cnt[i] : 0;
    sm[t] = c;
    __syncthreads();
    for (int off = 1; off < 256; off <<= 1){
        int v = (t >= off) ? sm[t-off] : 0;
        __syncthreads();
        sm[t] += v;
        __syncthreads();
    }
    if (i < N) rs[i] = sm[t] - c;          // local exclusive
    if (t == 255) part[blockIdx.x] = sm[255];
}

__global__ __launch_bounds__(256) void k_scan2(int* __restrict__ part, int nb){
    __shared__ int sm[256];
    int t = threadIdx.x;
    int c = (t < nb) ? part[t] : 0;
    sm[t] = c;
    __syncthreads();
    for (int off = 1; off < 256; off <<= 1){
        int v = (t >= off) ? sm[t-off] : 0;
        __syncthreads();
        sm[t] += v;
        __syncthreads();
    }
    if (t < nb) part[t] = sm[t] - c;       // exclusive block offsets
}

__global__ __launch_bounds__(256) void k_final(int* __restrict__ rs, const int* __restrict__ part,
                                               const int* __restrict__ cnt, float* __restrict__ dinv,
                                               int N, int E){
    int i = blockIdx.x*256 + threadIdx.x;
    if (i < N){
        rs[i] += part[i >> 8];
        dinv[i] = rsqrtf((float)cnt[i] + 1.0f);   // deg includes self-loop
    }
    if (i == 0) rs[N] = E;
}

__global__ __launch_bounds__(256) void k_fill(const int* __restrict__ src, const int* __restrict__ dst,
                                              const int* __restrict__ rs, int* __restrict__ fil,
                                              int* __restrict__ csr, int E){
    int e = blockIdx.x*256 + threadIdx.x;
    if (e < E){
        int d = dst[e];
        int p = atomicAdd(&fil[d], 1);
        csr[rs[d] + p] = src[e];
    }
}

// ---------------- dense matmul: C[n,128] = A[n,128] @ W[128,128] ----------------
// 128-row tile / block of 256 threads; thread = 4 rows x 16 cols; W in LDS.

__global__ __launch_bounds__(256) void k_mm(const float* __restrict__ A, const float* __restrict__ W,
                                            float* __restrict__ C, int n){
    __shared__ float sW[128*128];
    int t = threadIdx.x;
    for (int idx = t; idx < 4096; idx += 256)
        ((float4*)sW)[idx] = ((const float4*)W)[idx];
    __syncthreads();

    int tx = t & 7, ty = t >> 3;
    int c0 = tx * 16;
    int r0 = blockIdx.x * 128 + ty;

    float acc[4][16];
    #pragma unroll
    for (int i = 0; i < 4; ++i)
        #pragma unroll
        for (int j = 0; j < 16; ++j) acc[i][j] = 0.f;

    for (int k0 = 0; k0 < 128; k0 += 4){
        float4 a[4];
        #pragma unroll
        for (int i = 0; i < 4; ++i){
            int r = r0 + 32*i;
            a[i] = (r < n) ? *(const float4*)&A[(size_t)r*128 + k0] : make_float4(0.f,0.f,0.f,0.f);
        }
        #pragma unroll
        for (int kk = 0; kk < 4; ++kk){
            const float4* wp = (const float4*)&sW[(k0+kk)*128 + c0];
            float4 w0 = wp[0], w1 = wp[1], w2 = wp[2], w3 = wp[3];
            #pragma unroll
            for (int i = 0; i < 4; ++i){
                float av = (kk==0) ? a[i].x : (kk==1) ? a[i].y : (kk==2) ? a[i].z : a[i].w;
                acc[i][ 0] = fmaf(av, w0.x, acc[i][ 0]);
                acc[i][ 1] = fmaf(av, w0.y, acc[i][ 1]);
                acc[i][ 2] = fmaf(av, w0.z, acc[i][ 2]);
                acc[i][ 3] = fmaf(av, w0.w, acc[i][ 3]);
                acc[i][ 4] = fmaf(av, w1.x, acc[i][ 4]);
                acc[i][ 5] = fmaf(av, w1.y, acc[i][ 5]);
                acc[i][ 6] = fmaf(av, w1.z, acc[i][ 6]);
                acc[i][ 7] = fmaf(av, w1.w, acc[i][ 7]);
                acc[i][ 8] = fmaf(av, w2.x, acc[i][ 8]);
                acc[i][ 9] = fmaf(av, w2.y, acc[i][ 9]);
                acc[i][10] = fmaf(av, w2.z, acc[i][10]);
                acc[i][11] = fmaf(av, w2.w, acc[i][11]);
                acc[i][12] = fmaf(av, w3.x, acc[i][12]);
                acc[i][13] = fmaf(av, w3.y, acc[i][13]);
                acc[i][14] = fmaf(av, w3.z, acc[i][14]);
                acc[i][15] = fmaf(av, w3.w, acc[i][15]);
            }
        }
    }

    #pragma unroll
    for (int i = 0; i < 4; ++i){
        int r = r0 + 32*i;
        if (r < n){
            float4* cp = (float4*)&C[(size_t)r*128 + c0];
            cp[0] = make_float4(acc[i][ 0], acc[i][ 1], acc[i][ 2], acc[i][ 3]);
            cp[1] = make_float4(acc[i][ 4], acc[i][ 5], acc[i][ 6], acc[i][ 7]);
            cp[2] = make_float4(acc[i][ 8], acc[i][ 9], acc[i][10], acc[i][11]);
            cp[3] = make_float4(acc[i][12], acc[i][13], acc[i][14], acc[i][15]);
        }
    }
}

// ---------------- aggregation: one wave per node, float2 per lane ----------------

__global__ __launch_bounds__(256) void k_agg(const float* __restrict__ hw, const float* __restrict__ dinv,
                                             const int* __restrict__ rs, const int* __restrict__ csr,
                                             const float* __restrict__ bias, float* __restrict__ hout, int N){
    int wid  = (blockIdx.x*256 + threadIdx.x) >> 6;
    int lane = threadIdx.x & 63;
    if (wid >= N) return;
    const float2* hv = (const float2*)hw;
    float di = dinv[wid];
    float2 s2 = hv[(size_t)wid*64 + lane];
    float2 acc = make_float2(s2.x*di, s2.y*di);   // self-loop: (hw*di)*di at the end
    int e0 = rs[wid], e1 = rs[wid+1];
    for (int e = e0; e < e1; ++e){
        int s = csr[e];
        float ds = dinv[s];
        float2 v = hv[(size_t)s*64 + lane];
        acc.x = fmaf(v.x, ds, acc.x);
        acc.y = fmaf(v.y, ds, acc.y);
    }
    float2 b2 = ((const float2*)bias)[lane];
    float ox = fmaxf(fmaf(acc.x, di, b2.x), 0.f);
    float oy = fmaxf(fmaf(acc.y, di, b2.y), 0.f);
    ((float2*)hout)[(size_t)wid*64 + lane] = make_float2(ox, oy);
}

// layer 3: no relu; fused with global_add_pool and output head (dot with Wo)
__global__ __launch_bounds__(256) void k_agg_pool(const float* __restrict__ hw, const float* __restrict__ dinv,
                                                  const int* __restrict__ rs, const int* __restrict__ csr,
                                                  const float* __restrict__ bias, const float* __restrict__ Wo,
                                                  const int* __restrict__ batch, float* __restrict__ out, int N){
    int wid  = (blockIdx.x*256 + threadIdx.x) >> 6;
    int lane = threadIdx.x & 63;
    if (wid >= N) return;
    const float2* hv = (const float2*)hw;
    float di = dinv[wid];
    float2 s2 = hv[(size_t)wid*64 + lane];
    float2 acc = make_float2(s2.x*di, s2.y*di);
    int e0 = rs[wid], e1 = rs[wid+1];
    for (int e = e0; e < e1; ++e){
        int s = csr[e];
        float ds = dinv[s];
        float2 v = hv[(size_t)s*64 + lane];
        acc.x = fmaf(v.x, ds, acc.x);
        acc.y = fmaf(v.y, ds, acc.y);
    }
    float2 b2 = ((const float2*)bias)[lane];
    float2 w2 = ((const float2*)Wo)[lane];
    float ox = fmaf(acc.x, di, b2.x);
    float oy = fmaf(acc.y, di, b2.y);
    float sdot = ox*w2.x + oy*w2.y;
    #pragma unroll
    for (int off = 32; off > 0; off >>= 1)
        sdot += __shfl_down(sdot, off, 64);
    if (lane == 0) atomicAdd(&out[batch[wid]], sdot);
}

__global__ __launch_bounds__(256) void k_init_out(float* __restrict__ out, const float* __restrict__ bo, int G){
    int g = blockIdx.x*256 + threadIdx.x;
    if (g < G) out[g] = bo[0];
}

// ---------------- launch ----------------

extern "C" void kernel_launch(void* const* d_in, const int* in_sizes, int n_in,
                              void* d_out, int out_size, void* d_ws, size_t ws_size,
                              hipStream_t stream) {
    const float* x     = (const float*)d_in[0];
    const int*   ei    = (const int*)d_in[1];
    const int*   batch = (const int*)d_in[2];
    const float* W1 = (const float*)d_in[3];
    const float* b1 = (const float*)d_in[4];
    const float* W2 = (const float*)d_in[5];
    const float* b2 = (const float*)d_in[6];
    const float* W3 = (const float*)d_in[7];
    const float* b3 = (const float*)d_in[8];
    const float* Wo = (const float*)d_in[9];
    const float* bo = (const float*)d_in[10];

    int N = in_sizes[0] / 128;
    int E = in_sizes[1] / 2;
    int G = out_size;
    const int* srcI = ei;
    const int* dstI = ei + E;

    // workspace carve-up (256B aligned)
    char* p = (char*)d_ws;
    size_t off = 0;
    auto alloc = [&](size_t bytes) -> void* {
        void* r = p + off;
        off += (bytes + 255) & ~(size_t)255;
        return r;
    };
    float* hw   = (float*)alloc((size_t)N*128*sizeof(float));
    float* h    = (float*)alloc((size_t)N*128*sizeof(float));
    float* dinv = (float*)alloc((size_t)N*sizeof(float));
    int*   cnt  = (int*)alloc((size_t)N*sizeof(int));
    int*   fil  = (int*)alloc((size_t)N*sizeof(int));
    int*   rs   = (int*)alloc((size_t)(N+1)*sizeof(int));
    int*   part = (int*)alloc(1024);
    int*   csr  = (int*)alloc((size_t)E*sizeof(int));

    hipMemsetAsync(cnt, 0, (size_t)N*sizeof(int), stream);
    hipMemsetAsync(fil, 0, (size_t)N*sizeof(int), stream);

    int nbE = (E + 255)/256;
    int nbN = (N + 255)/256;   // 196 <= 256, required by k_scan2
    k_count<<<nbE, 256, 0, stream>>>(dstI, cnt, E);
    k_scan1<<<nbN, 256, 0, stream>>>(cnt, rs, part, N);
    k_scan2<<<1,   256, 0, stream>>>(part, nbN);
    k_final<<<nbN, 256, 0, stream>>>(rs, part, cnt, dinv, N, E);
    k_fill <<<nbE, 256, 0, stream>>>(srcI, dstI, rs, fil, csr, E);

    int nbM = (N + 127)/128;
    long long waves = (long long)N;
    int nbA = (int)((waves*64 + 255)/256);

    k_mm <<<nbM, 256, 0, stream>>>(x, W1, hw, N);
    k_agg<<<nbA, 256, 0, stream>>>(hw, dinv, rs, csr, b1, h, N);
    k_mm <<<nbM, 256, 0, stream>>>(h, W2, hw, N);
    k_agg<<<nbA, 256, 0, stream>>>(hw, dinv, rs, csr, b2, h, N);
    k_mm <<<nbM, 256, 0, stream>>>(h, W3, hw, N);
    k_init_out<<<(G + 255)/256, 256, 0, stream>>>((float*)d_out, bo, G);
    k_agg_pool<<<nbA, 256, 0, stream>>>(hw, dinv, rs, csr, b3, Wo, batch, (float*)d_out, N);
}

// Round 2
// 493.475 us; speedup vs baseline: 1.1648x; 1.1648x over previous
//
#include <hip/hip_runtime.h>

// ---------------- CSR build (padded to multiples of 8 per node) ----------------

__global__ __launch_bounds__(256) void k_count(const int* __restrict__ dst, int* __restrict__ cnt, int E){
    int e = blockIdx.x*256 + threadIdx.x;
    if (e < E) atomicAdd(&cnt[dst[e]], 1);
}

// scan over PADDED counts ((c+7)&~7)
__global__ __launch_bounds__(256) void k_scan1(const int* __restrict__ cnt, int* __restrict__ rs,
                                               int* __restrict__ part, int N){
    __shared__ int sm[256];
    int t = threadIdx.x;
    int i = blockIdx.x*256 + t;
    int c = (i < N) ? ((cnt[i] + 7) & ~7) : 0;
    sm[t] = c;
    __syncthreads();
    for (int off = 1; off < 256; off <<= 1){
        int v = (t >= off) ? sm[t-off] : 0;
        __syncthreads();
        sm[t] += v;
        __syncthreads();
    }
    if (i < N) rs[i] = sm[t] - c;          // local exclusive
    if (t == 255) part[blockIdx.x] = sm[255];
}

__global__ __launch_bounds__(256) void k_scan2(int* __restrict__ part, int nb){
    __shared__ int sm[256];
    int t = threadIdx.x;
    int c = (t < nb) ? part[t] : 0;
    sm[t] = c;
    __syncthreads();
    for (int off = 1; off < 256; off <<= 1){
        int v = (t >= off) ? sm[t-off] : 0;
        __syncthreads();
        sm[t] += v;
        __syncthreads();
    }
    if (t < nb) part[t] = sm[t] - c;       // exclusive block offsets
}

__global__ __launch_bounds__(256) void k_final(int* __restrict__ rs, const int* __restrict__ part,
                                               const int* __restrict__ cnt, float* __restrict__ dinv, int N){
    int i = blockIdx.x*256 + threadIdx.x;
    if (i < N){
        rs[i] += part[i >> 8];
        dinv[i] = rsqrtf((float)cnt[i] + 1.0f);   // deg includes self-loop
    }
}

// fill padding slots with index N (zeroed dummy row)
__global__ __launch_bounds__(256) void k_pad(const int* __restrict__ cnt, const int* __restrict__ rs,
                                             int* __restrict__ csr, int N){
    int i = blockIdx.x*256 + threadIdx.x;
    if (i < N){
        int c = cnt[i];
        int pc = (c + 7) & ~7;
        int e = rs[i];
        for (int q = c; q < pc; ++q) csr[e+q] = N;
    }
}

__global__ __launch_bounds__(256) void k_fill(const int* __restrict__ src, const int* __restrict__ dst,
                                              const int* __restrict__ rs, int* __restrict__ fil,
                                              int* __restrict__ csr, int E){
    int e = blockIdx.x*256 + threadIdx.x;
    if (e < E){
        int d = dst[e];
        int p = atomicAdd(&fil[d], 1);
        csr[rs[d] + p] = src[e];
    }
}

// ---------------- dense matmul: C[r,:] = (A[r,:] @ W) * dinv[r] ----------------
// 128-row tile / block of 256 threads; thread = 4 rows x 16 cols; W in LDS.

__global__ __launch_bounds__(256) void k_mm(const float* __restrict__ A, const float* __restrict__ W,
                                            const float* __restrict__ dinv, float* __restrict__ C, int n){
    __shared__ float sW[128*128];
    int t = threadIdx.x;
    for (int idx = t; idx < 4096; idx += 256)
        ((float4*)sW)[idx] = ((const float4*)W)[idx];
    __syncthreads();

    int tx = t & 7, ty = t >> 3;
    int c0 = tx * 16;
    int r0 = blockIdx.x * 128 + ty;

    float acc[4][16];
    #pragma unroll
    for (int i = 0; i < 4; ++i)
        #pragma unroll
        for (int j = 0; j < 16; ++j) acc[i][j] = 0.f;

    for (int k0 = 0; k0 < 128; k0 += 4){
        float4 a[4];
        #pragma unroll
        for (int i = 0; i < 4; ++i){
            int r = r0 + 32*i;
            a[i] = (r < n) ? *(const float4*)&A[(size_t)r*128 + k0] : make_float4(0.f,0.f,0.f,0.f);
        }
        #pragma unroll
        for (int kk = 0; kk < 4; ++kk){
            const float4* wp = (const float4*)&sW[(k0+kk)*128 + c0];
            float4 w0 = wp[0], w1 = wp[1], w2 = wp[2], w3 = wp[3];
            #pragma unroll
            for (int i = 0; i < 4; ++i){
                float av = (kk==0) ? a[i].x : (kk==1) ? a[i].y : (kk==2) ? a[i].z : a[i].w;
                acc[i][ 0] = fmaf(av, w0.x, acc[i][ 0]);
                acc[i][ 1] = fmaf(av, w0.y, acc[i][ 1]);
                acc[i][ 2] = fmaf(av, w0.z, acc[i][ 2]);
                acc[i][ 3] = fmaf(av, w0.w, acc[i][ 3]);
                acc[i][ 4] = fmaf(av, w1.x, acc[i][ 4]);
                acc[i][ 5] = fmaf(av, w1.y, acc[i][ 5]);
                acc[i][ 6] = fmaf(av, w1.z, acc[i][ 6]);
                acc[i][ 7] = fmaf(av, w1.w, acc[i][ 7]);
                acc[i][ 8] = fmaf(av, w2.x, acc[i][ 8]);
                acc[i][ 9] = fmaf(av, w2.y, acc[i][ 9]);
                acc[i][10] = fmaf(av, w2.z, acc[i][10]);
                acc[i][11] = fmaf(av, w2.w, acc[i][11]);
                acc[i][12] = fmaf(av, w3.x, acc[i][12]);
                acc[i][13] = fmaf(av, w3.y, acc[i][13]);
                acc[i][14] = fmaf(av, w3.z, acc[i][14]);
                acc[i][15] = fmaf(av, w3.w, acc[i][15]);
            }
        }
    }

    #pragma unroll
    for (int i = 0; i < 4; ++i){
        int r = r0 + 32*i;
        if (r < n){
            float di = dinv[r];
            float4* cp = (float4*)&C[(size_t)r*128 + c0];
            cp[0] = make_float4(acc[i][ 0]*di, acc[i][ 1]*di, acc[i][ 2]*di, acc[i][ 3]*di);
            cp[1] = make_float4(acc[i][ 4]*di, acc[i][ 5]*di, acc[i][ 6]*di, acc[i][ 7]*di);
            cp[2] = make_float4(acc[i][ 8]*di, acc[i][ 9]*di, acc[i][10]*di, acc[i][11]*di);
            cp[3] = make_float4(acc[i][12]*di, acc[i][13]*di, acc[i][14]*di, acc[i][15]*di);
        }
    }
}

// ---------------- aggregation: wave/node, batch-8 gathers, hwp pre-scaled ----------------

__global__ __launch_bounds__(256) void k_agg(const float* __restrict__ hwp, const float* __restrict__ dinv,
                                             const int* __restrict__ rs, const int* __restrict__ cnt,
                                             const int* __restrict__ csr, const float* __restrict__ bias,
                                             float* __restrict__ hout, int N){
    int wid  = (blockIdx.x*256 + threadIdx.x) >> 6;
    int lane = threadIdx.x & 63;
    if (wid >= N) return;
    const float2* hv = (const float2*)hwp;
    float2 acc = hv[(size_t)wid*64 + lane];          // self term (pre-scaled)
    int nb = (cnt[wid] + 7) >> 3;
    const int* cp = csr + rs[wid];
    for (int t = 0; t < nb; ++t){
        int4 ia = ((const int4*)cp)[0];
        int4 ib = ((const int4*)cp)[1];
        cp += 8;
        float2 v0 = hv[(size_t)ia.x*64 + lane];
        float2 v1 = hv[(size_t)ia.y*64 + lane];
        float2 v2 = hv[(size_t)ia.z*64 + lane];
        float2 v3 = hv[(size_t)ia.w*64 + lane];
        float2 v4 = hv[(size_t)ib.x*64 + lane];
        float2 v5 = hv[(size_t)ib.y*64 + lane];
        float2 v6 = hv[(size_t)ib.z*64 + lane];
        float2 v7 = hv[(size_t)ib.w*64 + lane];
        acc.x += ((v0.x+v1.x)+(v2.x+v3.x)) + ((v4.x+v5.x)+(v6.x+v7.x));
        acc.y += ((v0.y+v1.y)+(v2.y+v3.y)) + ((v4.y+v5.y)+(v6.y+v7.y));
    }
    float di = dinv[wid];
    float2 b2 = ((const float2*)bias)[lane];
    ((float2*)hout)[(size_t)wid*64 + lane] = make_float2(
        fmaxf(fmaf(acc.x, di, b2.x), 0.f),
        fmaxf(fmaf(acc.y, di, b2.y), 0.f));
}

// layer 3: no relu; fused with global_add_pool and output head (dot with Wo)
__global__ __launch_bounds__(256) void k_agg_pool(const float* __restrict__ hwp, const float* __restrict__ dinv,
                                                  const int* __restrict__ rs, const int* __restrict__ cnt,
                                                  const int* __restrict__ csr, const float* __restrict__ bias,
                                                  const float* __restrict__ Wo, const int* __restrict__ batch,
                                                  float* __restrict__ out, int N){
    int wid  = (blockIdx.x*256 + threadIdx.x) >> 6;
    int lane = threadIdx.x & 63;
    if (wid >= N) return;
    const float2* hv = (const float2*)hwp;
    float2 acc = hv[(size_t)wid*64 + lane];
    int nb = (cnt[wid] + 7) >> 3;
    const int* cp = csr + rs[wid];
    for (int t = 0; t < nb; ++t){
        int4 ia = ((const int4*)cp)[0];
        int4 ib = ((const int4*)cp)[1];
        cp += 8;
        float2 v0 = hv[(size_t)ia.x*64 + lane];
        float2 v1 = hv[(size_t)ia.y*64 + lane];
        float2 v2 = hv[(size_t)ia.z*64 + lane];
        float2 v3 = hv[(size_t)ia.w*64 + lane];
        float2 v4 = hv[(size_t)ib.x*64 + lane];
        float2 v5 = hv[(size_t)ib.y*64 + lane];
        float2 v6 = hv[(size_t)ib.z*64 + lane];
        float2 v7 = hv[(size_t)ib.w*64 + lane];
        acc.x += ((v0.x+v1.x)+(v2.x+v3.x)) + ((v4.x+v5.x)+(v6.x+v7.x));
        acc.y += ((v0.y+v1.y)+(v2.y+v3.y)) + ((v4.y+v5.y)+(v6.y+v7.y));
    }
    float di = dinv[wid];
    float2 b2 = ((const float2*)bias)[lane];
    float2 w2 = ((const float2*)Wo)[lane];
    float ox = fmaf(acc.x, di, b2.x);
    float oy = fmaf(acc.y, di, b2.y);
    float sdot = ox*w2.x + oy*w2.y;
    #pragma unroll
    for (int off = 32; off > 0; off >>= 1)
        sdot += __shfl_down(sdot, off, 64);
    if (lane == 0) atomicAdd(&out[batch[wid]], sdot);
}

__global__ __launch_bounds__(256) void k_init_out(float* __restrict__ out, const float* __restrict__ bo, int G){
    int g = blockIdx.x*256 + threadIdx.x;
    if (g < G) out[g] = bo[0];
}

// ---------------- launch ----------------

extern "C" void kernel_launch(void* const* d_in, const int* in_sizes, int n_in,
                              void* d_out, int out_size, void* d_ws, size_t ws_size,
                              hipStream_t stream) {
    const float* x     = (const float*)d_in[0];
    const int*   ei    = (const int*)d_in[1];
    const int*   batch = (const int*)d_in[2];
    const float* W1 = (const float*)d_in[3];
    const float* b1 = (const float*)d_in[4];
    const float* W2 = (const float*)d_in[5];
    const float* b2 = (const float*)d_in[6];
    const float* W3 = (const float*)d_in[7];
    const float* b3 = (const float*)d_in[8];
    const float* Wo = (const float*)d_in[9];
    const float* bo = (const float*)d_in[10];

    int N = in_sizes[0] / 128;
    int E = in_sizes[1] / 2;
    int G = out_size;
    const int* srcI = ei;
    const int* dstI = ei + E;

    // workspace carve-up (256B aligned)
    char* p = (char*)d_ws;
    size_t off = 0;
    auto alloc = [&](size_t bytes) -> void* {
        void* r = p + off;
        off += (bytes + 255) & ~(size_t)255;
        return r;
    };
    float* hw   = (float*)alloc((size_t)(N+1)*128*sizeof(float));  // row N = zero dummy
    float* h    = (float*)alloc((size_t)N*128*sizeof(float));
    float* dinv = (float*)alloc((size_t)N*sizeof(float));
    int*   cnt  = (int*)alloc((size_t)N*sizeof(int));
    int*   fil  = (int*)alloc((size_t)N*sizeof(int));
    int*   rs   = (int*)alloc((size_t)(N+1)*sizeof(int));
    int*   part = (int*)alloc(1024);
    int*   csr  = (int*)alloc(((size_t)E + 8*(size_t)N)*sizeof(int));  // padded

    hipMemsetAsync(cnt, 0, (size_t)N*sizeof(int), stream);
    hipMemsetAsync(fil, 0, (size_t)N*sizeof(int), stream);
    hipMemsetAsync((char*)hw + (size_t)N*128*sizeof(float), 0, 128*sizeof(float), stream); // zero dummy row

    int nbE = (E + 255)/256;
    int nbN = (N + 255)/256;   // 196 <= 256, required by k_scan2
    k_count<<<nbE, 256, 0, stream>>>(dstI, cnt, E);
    k_scan1<<<nbN, 256, 0, stream>>>(cnt, rs, part, N);
    k_scan2<<<1,   256, 0, stream>>>(part, nbN);
    k_final<<<nbN, 256, 0, stream>>>(rs, part, cnt, dinv, N);
    k_pad  <<<nbN, 256, 0, stream>>>(cnt, rs, csr, N);
    k_fill <<<nbE, 256, 0, stream>>>(srcI, dstI, rs, fil, csr, E);

    int nbM = (N + 127)/128;
    int nbA = (int)(((long long)N*64 + 255)/256);

    k_mm <<<nbM, 256, 0, stream>>>(x, W1, dinv, hw, N);
    k_agg<<<nbA, 256, 0, stream>>>(hw, dinv, rs, cnt, csr, b1, h, N);
    k_mm <<<nbM, 256, 0, stream>>>(h, W2, dinv, hw, N);
    k_agg<<<nbA, 256, 0, stream>>>(hw, dinv, rs, cnt, csr, b2, h, N);
    k_mm <<<nbM, 256, 0, stream>>>(h, W3, dinv, hw, N);
    k_init_out<<<(G + 255)/256, 256, 0, stream>>>((float*)d_out, bo, G);
    k_agg_pool<<<nbA, 256, 0, stream>>>(hw, dinv, rs, cnt, csr, b3, Wo, batch, (float*)d_out, N);
}

// Round 3
// 420.717 us; speedup vs baseline: 1.3663x; 1.1729x over previous
//
#include <hip/hip_runtime.h>

typedef _Float16 f16;
typedef __attribute__((ext_vector_type(2))) _Float16 f16x2;

__device__ inline float2 h2f(unsigned u){
    f16x2 h = __builtin_bit_cast(f16x2, u);
    return make_float2((float)h.x, (float)h.y);
}

// ---------------- CSR build (padded to multiples of 8 per node) ----------------

__global__ __launch_bounds__(256) void k_count(const int* __restrict__ dst, int* __restrict__ cnt, int E){
    int e = blockIdx.x*256 + threadIdx.x;
    if (e < E) atomicAdd(&cnt[dst[e]], 1);
}

// scan over PADDED counts ((c+7)&~7)
__global__ __launch_bounds__(256) void k_scan1(const int* __restrict__ cnt, int* __restrict__ rs,
                                               int* __restrict__ part, int N){
    __shared__ int sm[256];
    int t = threadIdx.x;
    int i = blockIdx.x*256 + t;
    int c = (i < N) ? ((cnt[i] + 7) & ~7) : 0;
    sm[t] = c;
    __syncthreads();
    for (int off = 1; off < 256; off <<= 1){
        int v = (t >= off) ? sm[t-off] : 0;
        __syncthreads();
        sm[t] += v;
        __syncthreads();
    }
    if (i < N) rs[i] = sm[t] - c;          // local exclusive
    if (t == 255) part[blockIdx.x] = sm[255];
}

__global__ __launch_bounds__(256) void k_scan2(int* __restrict__ part, int nb){
    __shared__ int sm[256];
    int t = threadIdx.x;
    int c = (t < nb) ? part[t] : 0;
    sm[t] = c;
    __syncthreads();
    for (int off = 1; off < 256; off <<= 1){
        int v = (t >= off) ? sm[t-off] : 0;
        __syncthreads();
        sm[t] += v;
        __syncthreads();
    }
    if (t < nb) part[t] = sm[t] - c;       // exclusive block offsets
}

__global__ __launch_bounds__(256) void k_final(int* __restrict__ rs, const int* __restrict__ part,
                                               const int* __restrict__ cnt, float* __restrict__ dinv, int N){
    int i = blockIdx.x*256 + threadIdx.x;
    if (i < N){
        rs[i] += part[i >> 8];
        dinv[i] = rsqrtf((float)cnt[i] + 1.0f);   // deg includes self-loop
    }
}

// fill padding slots with index N (zeroed dummy row)
__global__ __launch_bounds__(256) void k_pad(const int* __restrict__ cnt, const int* __restrict__ rs,
                                             int* __restrict__ csr, int N){
    int i = blockIdx.x*256 + threadIdx.x;
    if (i < N){
        int c = cnt[i];
        int pc = (c + 7) & ~7;
        int e = rs[i];
        for (int q = c; q < pc; ++q) csr[e+q] = N;
    }
}

__global__ __launch_bounds__(256) void k_fill(const int* __restrict__ src, const int* __restrict__ dst,
                                              const int* __restrict__ rs, int* __restrict__ fil,
                                              int* __restrict__ csr, int E){
    int e = blockIdx.x*256 + threadIdx.x;
    if (e < E){
        int d = dst[e];
        int p = atomicAdd(&fil[d], 1);
        csr[rs[d] + p] = src[e];
    }
}

// ---------------- dense matmul: C[r,:] = fp16((A[r,:] @ W) * dinv[r]) ----------------
// 128-row tile / block of 256 threads; thread = 4 rows x 16 cols; W in LDS.

__global__ __launch_bounds__(256) void k_mm(const float* __restrict__ A, const float* __restrict__ W,
                                            const float* __restrict__ dinv, f16* __restrict__ C, int n){
    __shared__ float sW[128*128];
    int t = threadIdx.x;
    for (int idx = t; idx < 4096; idx += 256)
        ((float4*)sW)[idx] = ((const float4*)W)[idx];
    __syncthreads();

    int tx = t & 7, ty = t >> 3;
    int c0 = tx * 16;
    int r0 = blockIdx.x * 128 + ty;

    float acc[4][16];
    #pragma unroll
    for (int i = 0; i < 4; ++i)
        #pragma unroll
        for (int j = 0; j < 16; ++j) acc[i][j] = 0.f;

    for (int k0 = 0; k0 < 128; k0 += 4){
        float4 a[4];
        #pragma unroll
        for (int i = 0; i < 4; ++i){
            int r = r0 + 32*i;
            a[i] = (r < n) ? *(const float4*)&A[(size_t)r*128 + k0] : make_float4(0.f,0.f,0.f,0.f);
        }
        #pragma unroll
        for (int kk = 0; kk < 4; ++kk){
            const float4* wp = (const float4*)&sW[(k0+kk)*128 + c0];
            float4 w0 = wp[0], w1 = wp[1], w2 = wp[2], w3 = wp[3];
            #pragma unroll
            for (int i = 0; i < 4; ++i){
                float av = (kk==0) ? a[i].x : (kk==1) ? a[i].y : (kk==2) ? a[i].z : a[i].w;
                acc[i][ 0] = fmaf(av, w0.x, acc[i][ 0]);
                acc[i][ 1] = fmaf(av, w0.y, acc[i][ 1]);
                acc[i][ 2] = fmaf(av, w0.z, acc[i][ 2]);
                acc[i][ 3] = fmaf(av, w0.w, acc[i][ 3]);
                acc[i][ 4] = fmaf(av, w1.x, acc[i][ 4]);
                acc[i][ 5] = fmaf(av, w1.y, acc[i][ 5]);
                acc[i][ 6] = fmaf(av, w1.z, acc[i][ 6]);
                acc[i][ 7] = fmaf(av, w1.w, acc[i][ 7]);
                acc[i][ 8] = fmaf(av, w2.x, acc[i][ 8]);
                acc[i][ 9] = fmaf(av, w2.y, acc[i][ 9]);
                acc[i][10] = fmaf(av, w2.z, acc[i][10]);
                acc[i][11] = fmaf(av, w2.w, acc[i][11]);
                acc[i][12] = fmaf(av, w3.x, acc[i][12]);
                acc[i][13] = fmaf(av, w3.y, acc[i][13]);
                acc[i][14] = fmaf(av, w3.z, acc[i][14]);
                acc[i][15] = fmaf(av, w3.w, acc[i][15]);
            }
        }
    }

    #pragma unroll
    for (int i = 0; i < 4; ++i){
        int r = r0 + 32*i;
        if (r < n){
            float di = dinv[r];
            unsigned u[8];
            #pragma unroll
            for (int j = 0; j < 8; ++j){
                f16x2 hp;
                hp.x = (f16)(acc[i][2*j]   * di);
                hp.y = (f16)(acc[i][2*j+1] * di);
                u[j] = __builtin_bit_cast(unsigned, hp);
            }
            uint4* cp = (uint4*)&C[(size_t)r*128 + c0];
            cp[0] = make_uint4(u[0],u[1],u[2],u[3]);
            cp[1] = make_uint4(u[4],u[5],u[6],u[7]);
        }
    }
}

// ---------------- aggregation: wave/node, batch-8 fp16 gathers, fp32 accum ----------------

__global__ __launch_bounds__(256) void k_agg(const f16* __restrict__ hwp, const float* __restrict__ dinv,
                                             const int* __restrict__ rs, const int* __restrict__ cnt,
                                             const int* __restrict__ csr, const float* __restrict__ bias,
                                             float* __restrict__ hout, int N){
    int wid  = (blockIdx.x*256 + threadIdx.x) >> 6;
    int lane = threadIdx.x & 63;
    if (wid >= N) return;
    wid = __builtin_amdgcn_readfirstlane(wid);
    const unsigned* hv = (const unsigned*)hwp;
    float2 acc = h2f(hv[(size_t)wid*64 + lane]);     // self term (pre-scaled)
    int nb = (cnt[wid] + 7) >> 3;
    const int* cp = csr + rs[wid];
    for (int t = 0; t < nb; ++t){
        int4 ia = ((const int4*)cp)[0];
        int4 ib = ((const int4*)cp)[1];
        cp += 8;
        unsigned u0 = hv[(size_t)ia.x*64 + lane];
        unsigned u1 = hv[(size_t)ia.y*64 + lane];
        unsigned u2 = hv[(size_t)ia.z*64 + lane];
        unsigned u3 = hv[(size_t)ia.w*64 + lane];
        unsigned u4 = hv[(size_t)ib.x*64 + lane];
        unsigned u5 = hv[(size_t)ib.y*64 + lane];
        unsigned u6 = hv[(size_t)ib.z*64 + lane];
        unsigned u7 = hv[(size_t)ib.w*64 + lane];
        float2 v0 = h2f(u0), v1 = h2f(u1), v2 = h2f(u2), v3 = h2f(u3);
        float2 v4 = h2f(u4), v5 = h2f(u5), v6 = h2f(u6), v7 = h2f(u7);
        acc.x += ((v0.x+v1.x)+(v2.x+v3.x)) + ((v4.x+v5.x)+(v6.x+v7.x));
        acc.y += ((v0.y+v1.y)+(v2.y+v3.y)) + ((v4.y+v5.y)+(v6.y+v7.y));
    }
    float di = dinv[wid];
    float2 b2 = ((const float2*)bias)[lane];
    ((float2*)hout)[(size_t)wid*64 + lane] = make_float2(
        fmaxf(fmaf(acc.x, di, b2.x), 0.f),
        fmaxf(fmaf(acc.y, di, b2.y), 0.f));
}

// layer 3: no relu; fused with global_add_pool and output head (dot with Wo)
__global__ __launch_bounds__(256) void k_agg_pool(const f16* __restrict__ hwp, const float* __restrict__ dinv,
                                                  const int* __restrict__ rs, const int* __restrict__ cnt,
                                                  const int* __restrict__ csr, const float* __restrict__ bias,
                                                  const float* __restrict__ Wo, const int* __restrict__ batch,
                                                  float* __restrict__ out, int N){
    int wid  = (blockIdx.x*256 + threadIdx.x) >> 6;
    int lane = threadIdx.x & 63;
    if (wid >= N) return;
    wid = __builtin_amdgcn_readfirstlane(wid);
    const unsigned* hv = (const unsigned*)hwp;
    float2 acc = h2f(hv[(size_t)wid*64 + lane]);
    int nb = (cnt[wid] + 7) >> 3;
    const int* cp = csr + rs[wid];
    for (int t = 0; t < nb; ++t){
        int4 ia = ((const int4*)cp)[0];
        int4 ib = ((const int4*)cp)[1];
        cp += 8;
        unsigned u0 = hv[(size_t)ia.x*64 + lane];
        unsigned u1 = hv[(size_t)ia.y*64 + lane];
        unsigned u2 = hv[(size_t)ia.z*64 + lane];
        unsigned u3 = hv[(size_t)ia.w*64 + lane];
        unsigned u4 = hv[(size_t)ib.x*64 + lane];
        unsigned u5 = hv[(size_t)ib.y*64 + lane];
        unsigned u6 = hv[(size_t)ib.z*64 + lane];
        unsigned u7 = hv[(size_t)ib.w*64 + lane];
        float2 v0 = h2f(u0), v1 = h2f(u1), v2 = h2f(u2), v3 = h2f(u3);
        float2 v4 = h2f(u4), v5 = h2f(u5), v6 = h2f(u6), v7 = h2f(u7);
        acc.x += ((v0.x+v1.x)+(v2.x+v3.x)) + ((v4.x+v5.x)+(v6.x+v7.x));
        acc.y += ((v0.y+v1.y)+(v2.y+v3.y)) + ((v4.y+v5.y)+(v6.y+v7.y));
    }
    float di = dinv[wid];
    float2 b2 = ((const float2*)bias)[lane];
    float2 w2 = ((const float2*)Wo)[lane];
    float ox = fmaf(acc.x, di, b2.x);
    float oy = fmaf(acc.y, di, b2.y);
    float sdot = ox*w2.x + oy*w2.y;
    #pragma unroll
    for (int off = 32; off > 0; off >>= 1)
        sdot += __shfl_down(sdot, off, 64);
    if (lane == 0) atomicAdd(&out[batch[wid]], sdot);
}

__global__ __launch_bounds__(256) void k_init_out(float* __restrict__ out, const float* __restrict__ bo, int G){
    int g = blockIdx.x*256 + threadIdx.x;
    if (g < G) out[g] = bo[0];
}

// ---------------- launch ----------------

extern "C" void kernel_launch(void* const* d_in, const int* in_sizes, int n_in,
                              void* d_out, int out_size, void* d_ws, size_t ws_size,
                              hipStream_t stream) {
    const float* x     = (const float*)d_in[0];
    const int*   ei    = (const int*)d_in[1];
    const int*   batch = (const int*)d_in[2];
    const float* W1 = (const float*)d_in[3];
    const float* b1 = (const float*)d_in[4];
    const float* W2 = (const float*)d_in[5];
    const float* b2 = (const float*)d_in[6];
    const float* W3 = (const float*)d_in[7];
    const float* b3 = (const float*)d_in[8];
    const float* Wo = (const float*)d_in[9];
    const float* bo = (const float*)d_in[10];

    int N = in_sizes[0] / 128;
    int E = in_sizes[1] / 2;
    int G = out_size;
    const int* srcI = ei;
    const int* dstI = ei + E;

    // workspace carve-up (256B aligned)
    char* p = (char*)d_ws;
    size_t off = 0;
    auto alloc = [&](size_t bytes) -> void* {
        void* r = p + off;
        off += (bytes + 255) & ~(size_t)255;
        return r;
    };
    f16*   hw   = (f16*)alloc((size_t)(N+1)*128*sizeof(f16));      // row N = zero dummy
    float* h    = (float*)alloc((size_t)N*128*sizeof(float));
    float* dinv = (float*)alloc((size_t)N*sizeof(float));
    int*   cnt  = (int*)alloc((size_t)N*sizeof(int));
    int*   fil  = (int*)alloc((size_t)N*sizeof(int));
    int*   rs   = (int*)alloc((size_t)(N+1)*sizeof(int));
    int*   part = (int*)alloc(1024);
    int*   csr  = (int*)alloc(((size_t)E + 8*(size_t)N)*sizeof(int));  // padded

    hipMemsetAsync(cnt, 0, (size_t)N*sizeof(int), stream);
    hipMemsetAsync(fil, 0, (size_t)N*sizeof(int), stream);
    hipMemsetAsync((char*)hw + (size_t)N*128*sizeof(f16), 0, 128*sizeof(f16), stream); // zero dummy row

    int nbE = (E + 255)/256;
    int nbN = (N + 255)/256;   // 196 <= 256, required by k_scan2
    k_count<<<nbE, 256, 0, stream>>>(dstI, cnt, E);
    k_scan1<<<nbN, 256, 0, stream>>>(cnt, rs, part, N);
    k_scan2<<<1,   256, 0, stream>>>(part, nbN);
    k_final<<<nbN, 256, 0, stream>>>(rs, part, cnt, dinv, N);
    k_pad  <<<nbN, 256, 0, stream>>>(cnt, rs, csr, N);
    k_fill <<<nbE, 256, 0, stream>>>(srcI, dstI, rs, fil, csr, E);

    int nbM = (N + 127)/128;
    int nbA = (int)(((long long)N*64 + 255)/256);

    k_mm <<<nbM, 256, 0, stream>>>(x, W1, dinv, hw, N);
    k_agg<<<nbA, 256, 0, stream>>>(hw, dinv, rs, cnt, csr, b1, h, N);
    k_mm <<<nbM, 256, 0, stream>>>(h, W2, dinv, hw, N);
    k_agg<<<nbA, 256, 0, stream>>>(hw, dinv, rs, cnt, csr, b2, h, N);
    k_mm <<<nbM, 256, 0, stream>>>(h, W3, dinv, hw, N);
    k_init_out<<<(G + 255)/256, 256, 0, stream>>>((float*)d_out, bo, G);
    k_agg_pool<<<nbA, 256, 0, stream>>>(hw, dinv, rs, cnt, csr, b3, Wo, batch, (float*)d_out, N);
}

// Round 4
// 402.474 us; speedup vs baseline: 1.4282x; 1.0453x over previous
//
#include <hip/hip_runtime.h>

typedef _Float16 f16;
typedef __attribute__((ext_vector_type(2))) _Float16 f16x2;

__device__ inline float2 h2f(unsigned u){
    f16x2 h = __builtin_bit_cast(f16x2, u);
    return make_float2((float)h.x, (float)h.y);
}

// ---------------- CSR build (padded to multiples of 16 per node) ----------------

__global__ __launch_bounds__(256) void k_count(const int* __restrict__ dst, int* __restrict__ cnt, int E){
    int e = blockIdx.x*256 + threadIdx.x;
    if (e < E) atomicAdd(&cnt[dst[e]], 1);
}

// scan over PADDED counts ((c+15)&~15)
__global__ __launch_bounds__(256) void k_scan1(const int* __restrict__ cnt, int* __restrict__ rs,
                                               int* __restrict__ part, int N){
    __shared__ int sm[256];
    int t = threadIdx.x;
    int i = blockIdx.x*256 + t;
    int c = (i < N) ? ((cnt[i] + 15) & ~15) : 0;
    sm[t] = c;
    __syncthreads();
    for (int off = 1; off < 256; off <<= 1){
        int v = (t >= off) ? sm[t-off] : 0;
        __syncthreads();
        sm[t] += v;
        __syncthreads();
    }
    if (i < N) rs[i] = sm[t] - c;          // local exclusive
    if (t == 255) part[blockIdx.x] = sm[255];
}

__global__ __launch_bounds__(256) void k_scan2(int* __restrict__ part, int nb){
    __shared__ int sm[256];
    int t = threadIdx.x;
    int c = (t < nb) ? part[t] : 0;
    sm[t] = c;
    __syncthreads();
    for (int off = 1; off < 256; off <<= 1){
        int v = (t >= off) ? sm[t-off] : 0;
        __syncthreads();
        sm[t] += v;
        __syncthreads();
    }
    if (t < nb) part[t] = sm[t] - c;       // exclusive block offsets
}

__global__ __launch_bounds__(256) void k_final(int* __restrict__ rs, const int* __restrict__ part,
                                               const int* __restrict__ cnt, float* __restrict__ dinv, int N){
    int i = blockIdx.x*256 + threadIdx.x;
    if (i < N){
        rs[i] += part[i >> 8];
        dinv[i] = rsqrtf((float)cnt[i] + 1.0f);   // deg includes self-loop
    }
}

// fill padding slots with index N (zeroed dummy row)
__global__ __launch_bounds__(256) void k_pad(const int* __restrict__ cnt, const int* __restrict__ rs,
                                             int* __restrict__ csr, int N){
    int i = blockIdx.x*256 + threadIdx.x;
    if (i < N){
        int c = cnt[i];
        int pc = (c + 15) & ~15;
        int e = rs[i];
        for (int q = c; q < pc; ++q) csr[e+q] = N;
    }
}

__global__ __launch_bounds__(256) void k_fill(const int* __restrict__ src, const int* __restrict__ dst,
                                              const int* __restrict__ rs, int* __restrict__ fil,
                                              int* __restrict__ csr, int E){
    int e = blockIdx.x*256 + threadIdx.x;
    if (e < E){
        int d = dst[e];
        int p = atomicAdd(&fil[d], 1);
        csr[rs[d] + p] = src[e];
    }
}

// ---------------- dense matmul: C[r,:] = fp16((A[r,:] @ W) * dinv[r]) ----------------

__global__ __launch_bounds__(256) void k_mm(const float* __restrict__ A, const float* __restrict__ W,
                                            const float* __restrict__ dinv, f16* __restrict__ C, int n){
    __shared__ float sW[128*128];
    int t = threadIdx.x;
    for (int idx = t; idx < 4096; idx += 256)
        ((float4*)sW)[idx] = ((const float4*)W)[idx];
    __syncthreads();

    int tx = t & 7, ty = t >> 3;
    int c0 = tx * 16;
    int r0 = blockIdx.x * 128 + ty;

    float acc[4][16];
    #pragma unroll
    for (int i = 0; i < 4; ++i)
        #pragma unroll
        for (int j = 0; j < 16; ++j) acc[i][j] = 0.f;

    for (int k0 = 0; k0 < 128; k0 += 4){
        float4 a[4];
        #pragma unroll
        for (int i = 0; i < 4; ++i){
            int r = r0 + 32*i;
            a[i] = (r < n) ? *(const float4*)&A[(size_t)r*128 + k0] : make_float4(0.f,0.f,0.f,0.f);
        }
        #pragma unroll
        for (int kk = 0; kk < 4; ++kk){
            const float4* wp = (const float4*)&sW[(k0+kk)*128 + c0];
            float4 w0 = wp[0], w1 = wp[1], w2 = wp[2], w3 = wp[3];
            #pragma unroll
            for (int i = 0; i < 4; ++i){
                float av = (kk==0) ? a[i].x : (kk==1) ? a[i].y : (kk==2) ? a[i].z : a[i].w;
                acc[i][ 0] = fmaf(av, w0.x, acc[i][ 0]);
                acc[i][ 1] = fmaf(av, w0.y, acc[i][ 1]);
                acc[i][ 2] = fmaf(av, w0.z, acc[i][ 2]);
                acc[i][ 3] = fmaf(av, w0.w, acc[i][ 3]);
                acc[i][ 4] = fmaf(av, w1.x, acc[i][ 4]);
                acc[i][ 5] = fmaf(av, w1.y, acc[i][ 5]);
                acc[i][ 6] = fmaf(av, w1.z, acc[i][ 6]);
                acc[i][ 7] = fmaf(av, w1.w, acc[i][ 7]);
                acc[i][ 8] = fmaf(av, w2.x, acc[i][ 8]);
                acc[i][ 9] = fmaf(av, w2.y, acc[i][ 9]);
                acc[i][10] = fmaf(av, w2.z, acc[i][10]);
                acc[i][11] = fmaf(av, w2.w, acc[i][11]);
                acc[i][12] = fmaf(av, w3.x, acc[i][12]);
                acc[i][13] = fmaf(av, w3.y, acc[i][13]);
                acc[i][14] = fmaf(av, w3.z, acc[i][14]);
                acc[i][15] = fmaf(av, w3.w, acc[i][15]);
            }
        }
    }

    #pragma unroll
    for (int i = 0; i < 4; ++i){
        int r = r0 + 32*i;
        if (r < n){
            float di = dinv[r];
            unsigned u[8];
            #pragma unroll
            for (int j = 0; j < 8; ++j){
                f16x2 hp;
                hp.x = (f16)(acc[i][2*j]   * di);
                hp.y = (f16)(acc[i][2*j+1] * di);
                u[j] = __builtin_bit_cast(unsigned, hp);
            }
            uint4* cp = (uint4*)&C[(size_t)r*128 + c0];
            cp[0] = make_uint4(u[0],u[1],u[2],u[3]);
            cp[1] = make_uint4(u[4],u[5],u[6],u[7]);
        }
    }
}

// ---------------- aggregation: wave/node; 16B/lane gathers; 4 rows per instr ----------------
// lane = 16*g + c : group g in [0,4) handles rows, chunk c in [0,16) handles dims 8c..8c+7.

#define ADD8(u) { \
    float2 p0 = h2f((u).x), p1 = h2f((u).y), p2 = h2f((u).z), p3 = h2f((u).w); \
    acc[0] += p0.x; acc[1] += p0.y; acc[2] += p1.x; acc[3] += p1.y; \
    acc[4] += p2.x; acc[5] += p2.y; acc[6] += p3.x; acc[7] += p3.y; }

__global__ __launch_bounds__(256) void k_agg(const f16* __restrict__ hwp, const float* __restrict__ dinv,
                                             const int* __restrict__ rs, const int* __restrict__ cnt,
                                             const int* __restrict__ csr, const float* __restrict__ bias,
                                             float* __restrict__ hout, int N){
    int wid  = (blockIdx.x*256 + threadIdx.x) >> 6;
    int lane = threadIdx.x & 63;
    if (wid >= N) return;
    wid = __builtin_amdgcn_readfirstlane(wid);
    int g = lane >> 4, c = lane & 15;
    const uint4* rows = (const uint4*)hwp;   // 16 uint4 per row

    float acc[8];
    #pragma unroll
    for (int j = 0; j < 8; ++j) acc[j] = 0.f;

    // self row (pre-scaled): group 0 loads it, others hit the zero dummy row
    {
        uint4 s = rows[(size_t)((g == 0) ? wid : N)*16 + c];
        ADD8(s);
    }

    int nb = (cnt[wid] + 15) >> 4;
    const int* cp = csr + rs[wid];
    for (int t = 0; t < nb; ++t){
        int4 iv = ((const int4*)cp)[g];
        cp += 16;
        uint4 r0 = rows[(size_t)iv.x*16 + c];
        uint4 r1 = rows[(size_t)iv.y*16 + c];
        uint4 r2 = rows[(size_t)iv.z*16 + c];
        uint4 r3 = rows[(size_t)iv.w*16 + c];
        ADD8(r0); ADD8(r1); ADD8(r2); ADD8(r3);
    }

    #pragma unroll
    for (int j = 0; j < 8; ++j){
        acc[j] += __shfl_xor(acc[j], 16);
        acc[j] += __shfl_xor(acc[j], 32);
    }

    float di = dinv[wid];
    if (lane < 16){
        const float4* bp = (const float4*)bias + lane*2;
        float4 b0 = bp[0], b1 = bp[1];
        float4 o0 = make_float4(fmaxf(fmaf(acc[0],di,b0.x),0.f), fmaxf(fmaf(acc[1],di,b0.y),0.f),
                                fmaxf(fmaf(acc[2],di,b0.z),0.f), fmaxf(fmaf(acc[3],di,b0.w),0.f));
        float4 o1 = make_float4(fmaxf(fmaf(acc[4],di,b1.x),0.f), fmaxf(fmaf(acc[5],di,b1.y),0.f),
                                fmaxf(fmaf(acc[6],di,b1.z),0.f), fmaxf(fmaf(acc[7],di,b1.w),0.f));
        float4* op = (float4*)&hout[(size_t)wid*128 + lane*8];
        op[0] = o0; op[1] = o1;
    }
}

// layer 3: no relu; fused with global_add_pool and output head (dot with Wo)
__global__ __launch_bounds__(256) void k_agg_pool(const f16* __restrict__ hwp, const float* __restrict__ dinv,
                                                  const int* __restrict__ rs, const int* __restrict__ cnt,
                                                  const int* __restrict__ csr, const float* __restrict__ bias,
                                                  const float* __restrict__ Wo, const int* __restrict__ batch,
                                                  float* __restrict__ out, int N){
    int wid  = (blockIdx.x*256 + threadIdx.x) >> 6;
    int lane = threadIdx.x & 63;
    if (wid >= N) return;
    wid = __builtin_amdgcn_readfirstlane(wid);
    int g = lane >> 4, c = lane & 15;
    const uint4* rows = (const uint4*)hwp;

    float acc[8];
    #pragma unroll
    for (int j = 0; j < 8; ++j) acc[j] = 0.f;

    {
        uint4 s = rows[(size_t)((g == 0) ? wid : N)*16 + c];
        ADD8(s);
    }

    int nb = (cnt[wid] + 15) >> 4;
    const int* cp = csr + rs[wid];
    for (int t = 0; t < nb; ++t){
        int4 iv = ((const int4*)cp)[g];
        cp += 16;
        uint4 r0 = rows[(size_t)iv.x*16 + c];
        uint4 r1 = rows[(size_t)iv.y*16 + c];
        uint4 r2 = rows[(size_t)iv.z*16 + c];
        uint4 r3 = rows[(size_t)iv.w*16 + c];
        ADD8(r0); ADD8(r1); ADD8(r2); ADD8(r3);
    }

    #pragma unroll
    for (int j = 0; j < 8; ++j){
        acc[j] += __shfl_xor(acc[j], 16);
        acc[j] += __shfl_xor(acc[j], 32);
    }

    float di = dinv[wid];
    const float4* bp = (const float4*)bias + c*2;
    const float4* wp = (const float4*)Wo   + c*2;
    float4 b0 = bp[0], b1 = bp[1];
    float4 w0 = wp[0], w1 = wp[1];
    float sdot = fmaf(acc[0],di,b0.x)*w0.x + fmaf(acc[1],di,b0.y)*w0.y
               + fmaf(acc[2],di,b0.z)*w0.z + fmaf(acc[3],di,b0.w)*w0.w
               + fmaf(acc[4],di,b1.x)*w1.x + fmaf(acc[5],di,b1.y)*w1.y
               + fmaf(acc[6],di,b1.z)*w1.z + fmaf(acc[7],di,b1.w)*w1.w;
    sdot += __shfl_xor(sdot, 1);
    sdot += __shfl_xor(sdot, 2);
    sdot += __shfl_xor(sdot, 4);
    sdot += __shfl_xor(sdot, 8);
    if (lane == 0) atomicAdd(&out[batch[wid]], sdot);
}

__global__ __launch_bounds__(256) void k_init_out(float* __restrict__ out, const float* __restrict__ bo, int G){
    int g = blockIdx.x*256 + threadIdx.x;
    if (g < G) out[g] = bo[0];
}

// ---------------- launch ----------------

extern "C" void kernel_launch(void* const* d_in, const int* in_sizes, int n_in,
                              void* d_out, int out_size, void* d_ws, size_t ws_size,
                              hipStream_t stream) {
    const float* x     = (const float*)d_in[0];
    const int*   ei    = (const int*)d_in[1];
    const int*   batch = (const int*)d_in[2];
    const float* W1 = (const float*)d_in[3];
    const float* b1 = (const float*)d_in[4];
    const float* W2 = (const float*)d_in[5];
    const float* b2 = (const float*)d_in[6];
    const float* W3 = (const float*)d_in[7];
    const float* b3 = (const float*)d_in[8];
    const float* Wo = (const float*)d_in[9];
    const float* bo = (const float*)d_in[10];

    int N = in_sizes[0] / 128;
    int E = in_sizes[1] / 2;
    int G = out_size;
    const int* srcI = ei;
    const int* dstI = ei + E;

    char* p = (char*)d_ws;
    size_t off = 0;
    auto alloc = [&](size_t bytes) -> void* {
        void* r = p + off;
        off += (bytes + 255) & ~(size_t)255;
        return r;
    };
    f16*   hw   = (f16*)alloc((size_t)(N+1)*128*sizeof(f16));      // row N = zero dummy
    float* h    = (float*)alloc((size_t)N*128*sizeof(float));
    float* dinv = (float*)alloc((size_t)N*sizeof(float));
    int*   cnt  = (int*)alloc((size_t)N*sizeof(int));
    int*   fil  = (int*)alloc((size_t)N*sizeof(int));
    int*   rs   = (int*)alloc((size_t)(N+1)*sizeof(int));
    int*   part = (int*)alloc(1024);
    int*   csr  = (int*)alloc(((size_t)E + 16*(size_t)N)*sizeof(int));  // padded to 16

    hipMemsetAsync(cnt, 0, (size_t)N*sizeof(int), stream);
    hipMemsetAsync(fil, 0, (size_t)N*sizeof(int), stream);
    hipMemsetAsync((char*)hw + (size_t)N*128*sizeof(f16), 0, 128*sizeof(f16), stream); // zero dummy row

    int nbE = (E + 255)/256;
    int nbN = (N + 255)/256;   // 196 <= 256, required by k_scan2
    k_count<<<nbE, 256, 0, stream>>>(dstI, cnt, E);
    k_scan1<<<nbN, 256, 0, stream>>>(cnt, rs, part, N);
    k_scan2<<<1,   256, 0, stream>>>(part, nbN);
    k_final<<<nbN, 256, 0, stream>>>(rs, part, cnt, dinv, N);
    k_pad  <<<nbN, 256, 0, stream>>>(cnt, rs, csr, N);
    k_fill <<<nbE, 256, 0, stream>>>(srcI, dstI, rs, fil, csr, E);

    int nbM = (N + 127)/128;
    int nbA = (int)(((long long)N*64 + 255)/256);

    k_mm <<<nbM, 256, 0, stream>>>(x, W1, dinv, hw, N);
    k_agg<<<nbA, 256, 0, stream>>>(hw, dinv, rs, cnt, csr, b1, h, N);
    k_mm <<<nbM, 256, 0, stream>>>(h, W2, dinv, hw, N);
    k_agg<<<nbA, 256, 0, stream>>>(hw, dinv, rs, cnt, csr, b2, h, N);
    k_mm <<<nbM, 256, 0, stream>>>(h, W3, dinv, hw, N);
    k_init_out<<<(G + 255)/256, 256, 0, stream>>>((float*)d_out, bo, G);
    k_agg_pool<<<nbA, 256, 0, stream>>>(hw, dinv, rs, cnt, csr, b3, Wo, batch, (float*)d_out, N);
}